// Round 18
// baseline (795.724 us; speedup 1.0000x reference)
//
#include <hip/hip_runtime.h>
#include <hip/hip_bf16.h>

typedef __bf16 bf16;
typedef __attribute__((ext_vector_type(4))) float f32x4;
typedef __attribute__((ext_vector_type(8))) __bf16 bf16x8;
typedef __attribute__((ext_vector_type(4))) __bf16 bf16x4;

// async global->LDS, 16B per lane; LDS dest must be wave-uniform base + lane*16
static __device__ __forceinline__ void gl16(const void* g, void* l) {
  __builtin_amdgcn_global_load_lds((const __attribute__((address_space(1))) void*)g,
                                   (__attribute__((address_space(3))) void*)l, 16, 0, 0);
}
// fragment read from a [*][64] bf16 tile, 16B-unit XOR swizzle by (row&7)
static __device__ __forceinline__ bf16x8 frag(const bf16* tile, int row, int kb) {
  return *(const bf16x8*)(tile + row * 64 + ((((kb) >> 3) ^ (row & 7)) << 3));
}

// ---------------------------------------------------------------------------
// Weight prepass: 4x [256][256] f32 -> bf16 row-major.
// ---------------------------------------------------------------------------
__global__ void wpre(const float* __restrict__ w0, const float* __restrict__ w1,
                     const float* __restrict__ w2, const float* __restrict__ w3,
                     bf16* __restrict__ dst) {
  const float* srcs[4] = {w0, w1, w2, w3};
  const float* s = srcs[blockIdx.y];
  bf16* d = dst + (size_t)blockIdx.y * 65536;
  int base = blockIdx.x * 2048 + threadIdx.x * 8;
  f32x4 a = *(const f32x4*)(s + base);
  f32x4 b = *(const f32x4*)(s + base + 4);
  bf16x8 v = {(bf16)a[0], (bf16)a[1], (bf16)a[2], (bf16)a[3],
              (bf16)b[0], (bf16)b[1], (bf16)b[2], (bf16)b[3]};
  *(bf16x8*)(d + base) = v;
}

// ---------------------------------------------------------------------------
// wq f32 [o][i] -> wqT bf16 [i][o]  (LDS tile transpose, tiny)
// ---------------------------------------------------------------------------
__global__ void wtr(const float* __restrict__ wq, bf16* __restrict__ wqT) {
  __shared__ float tl[64][65];
  const int r0 = blockIdx.x * 64, c0 = blockIdx.y * 64;
  const int t = threadIdx.x;
  const int cc = t & 63, rr = t >> 6;
#pragma unroll
  for (int i = 0; i < 16; ++i) {
    int r = i * 4 + rr;
    tl[r][cc] = wq[(size_t)(r0 + r) * 256 + c0 + cc];
  }
  __syncthreads();
#pragma unroll
  for (int i = 0; i < 16; ++i) {
    int r = i * 4 + rr;
    wqT[(size_t)(c0 + r) * 256 + r0 + cc] = (bf16)tl[cc][r];
  }
}

// ===========================================================================
// K+V projection (unchanged).
// ===========================================================================
__global__ __launch_bounds__(256, 1)
void kv_proj(const float* __restrict__ key,
             const bf16* __restrict__ Wk, const float* __restrict__ bk, bf16* __restrict__ Kpm,
             const bf16* __restrict__ Wv, const float* __restrict__ bv, bf16* __restrict__ Vpm) {
  __shared__ alignas(16) char smem[64 * 264 * 2];
  const int P = 1600;
  const int t = threadIdx.x;
  const int b = blockIdx.z;
  const int p0 = blockIdx.x * 64;
  const int sel = blockIdx.y;
  const bf16* W = sel ? Wv : Wk;
  const float* bias = sel ? bv : bk;
  bf16* out = sel ? Vpm : Kpm;
  const int w = t >> 6, l = t & 63;
  const int lrow = l & 15, ksel = l >> 4;
  const int pq = t & 15, cq = t >> 4;
  const float* actb = key + (size_t)b * 256 * P;
  bf16* As = (bf16*)smem;

  f32x4 Ar[4][4];
#pragma unroll
  for (int kt = 0; kt < 4; ++kt)
#pragma unroll
    for (int j = 0; j < 4; ++j)
      Ar[kt][j] = *(const f32x4*)(actb + (size_t)(kt * 64 + cq * 4 + j) * P + p0 + pq * 4);
#pragma unroll
  for (int kt = 0; kt < 4; ++kt) {
    bf16* tile = As + kt * 4096;
#pragma unroll
    for (int e = 0; e < 4; ++e) {
      int row = pq * 4 + e;
      bf16x4 v = {(bf16)Ar[kt][0][e], (bf16)Ar[kt][1][e], (bf16)Ar[kt][2][e], (bf16)Ar[kt][3][e]};
      *(bf16x4*)(tile + row * 64 + ((((cq >> 1) ^ (row & 7)) << 3) | ((cq & 1) << 2))) = v;
    }
  }
  __syncthreads();

  f32x4 acc[4][4];
#pragma unroll
  for (int i = 0; i < 4; ++i)
#pragma unroll
    for (int j = 0; j < 4; ++j) acc[i][j] = (f32x4){0.f, 0.f, 0.f, 0.f};

#pragma unroll
  for (int kt = 0; kt < 4; ++kt) {
    const int k0 = kt * 64;
    const bf16* tile = As + kt * 4096;
    bf16x8 af[4][2], bv8[4][2];
#pragma unroll
    for (int mi = 0; mi < 4; ++mi)
#pragma unroll
      for (int kk = 0; kk < 2; ++kk)
        af[mi][kk] = *(const bf16x8*)(W + (size_t)(w * 64 + mi * 16 + lrow) * 256 +
                                      k0 + kk * 32 + ksel * 8);
#pragma unroll
    for (int ni = 0; ni < 4; ++ni)
#pragma unroll
      for (int kk = 0; kk < 2; ++kk)
        bv8[ni][kk] = frag(tile, ni * 16 + lrow, kk * 32 + ksel * 8);
#pragma unroll
    for (int kk = 0; kk < 2; ++kk)
#pragma unroll
      for (int mi = 0; mi < 4; ++mi)
#pragma unroll
        for (int ni = 0; ni < 4; ++ni)
          acc[mi][ni] = __builtin_amdgcn_mfma_f32_16x16x32_bf16(af[mi][kk], bv8[ni][kk],
                                                                acc[mi][ni], 0, 0, 0);
  }
  __syncthreads();

  bf16* Sc = (bf16*)smem;
#pragma unroll
  for (int mi = 0; mi < 4; ++mi) {
#pragma unroll
    for (int r = 0; r < 4; ++r) {
      int o = w * 64 + mi * 16 + ksel * 4 + r;
      float bvf = bias[o];
#pragma unroll
      for (int ni = 0; ni < 4; ++ni) {
        int px = ni * 16 + lrow;
        Sc[px * 264 + o] = (bf16)(acc[mi][ni][r] + bvf);
      }
    }
  }
  __syncthreads();
  bf16* ob = out + (size_t)b * P * 256 + (size_t)p0 * 256;
#pragma unroll
  for (int pass = 0; pass < 8; ++pass) {
    int idx = pass * 256 + t;
    int row = idx >> 5, cu = idx & 31;
    bf16x8 v = *(const bf16x8*)(Sc + row * 264 + cu * 8);
    *(bf16x8*)(ob + (size_t)row * 256 + cu * 8) = v;
  }
}

// ===========================================================================
// uv_gemm: D[b*4+hd][o][q] = sum_{c<64} A[o][hd*64+c] * Bpm[b*1600+q][hd*64+c]
// Used twice: (Kpm, wqT) -> T   and   (Vpm, wo) -> Uv.
// ===========================================================================
__global__ __launch_bounds__(256, 4)
void uv_gemm(const bf16* __restrict__ Bpm, const bf16* __restrict__ A,
             bf16* __restrict__ D) {
  __shared__ alignas(16) bf16 Vt[64 * 64];
  const int t = threadIdx.x;
  const int b = blockIdx.z;
  const int hd = blockIdx.y;
  const int q0 = blockIdx.x * 64;
  const int w = t >> 6, l = t & 63;
  const int lrow = l & 15, ksel = l >> 4;

  const bf16* vsrc = Bpm + ((size_t)b * 1600 + q0) * 256 + hd * 64;
#pragma unroll
  for (int call = 0; call < 2; ++call) {
    int idx = (w * 2 + call) * 64 + l;
    int q = idx >> 3, u = idx & 7;
    gl16(vsrc + (size_t)q * 256 + ((u ^ (q & 7)) << 3), Vt + idx * 8);
  }
  asm volatile("s_waitcnt vmcnt(0)" ::: "memory");
  __syncthreads();

  f32x4 acc[4][4];
#pragma unroll
  for (int i = 0; i < 4; ++i)
#pragma unroll
    for (int j = 0; j < 4; ++j) acc[i][j] = (f32x4){0.f, 0.f, 0.f, 0.f};

#pragma unroll
  for (int kk = 0; kk < 2; ++kk) {
    bf16x8 af[4], bv[4];
#pragma unroll
    for (int mi = 0; mi < 4; ++mi)
      af[mi] = *(const bf16x8*)(A + (size_t)(w * 64 + mi * 16 + lrow) * 256 +
                                hd * 64 + kk * 32 + ksel * 8);
#pragma unroll
    for (int ni = 0; ni < 4; ++ni)
      bv[ni] = frag(Vt, ni * 16 + lrow, kk * 32 + ksel * 8);
#pragma unroll
    for (int mi = 0; mi < 4; ++mi)
#pragma unroll
      for (int ni = 0; ni < 4; ++ni)
        acc[mi][ni] = __builtin_amdgcn_mfma_f32_16x16x32_bf16(af[mi], bv[ni], acc[mi][ni], 0, 0, 0);
  }

  bf16* ob = D + ((size_t)(b * 4 + hd)) * 256 * 1600;
#pragma unroll
  for (int mi = 0; mi < 4; ++mi) {
#pragma unroll
    for (int ni = 0; ni < 4; ++ni) {
#pragma unroll
      for (int r = 0; r < 4; ++r) {
        int o = w * 64 + mi * 16 + ksel * 4 + r;
        int q = q0 + ni * 16 + lrow;
        ob[(size_t)o * 1600 + q] = (bf16)acc[mi][ni][r];
      }
    }
  }
}

// ---------------------------------------------------------------------------
// beta[b][hd][q] = sum_{c<64} bq[hd*64+c] * Kpm[b*1600+q][hd*64+c]   (bf16)
// ---------------------------------------------------------------------------
__global__ void beta_k(const bf16* __restrict__ Kpm, const float* __restrict__ bq,
                       bf16* __restrict__ beta) {
  __shared__ float bqs[256];
  const int t = threadIdx.x;
  bqs[t] = bq[t];
  __syncthreads();
  const int b = blockIdx.y;
  const int q = blockIdx.x * 64 + (t >> 2);
  const int hd = t & 3;
  const bf16* row = Kpm + ((size_t)b * 1600 + q) * 256 + hd * 64;
  float s = 0.f;
#pragma unroll
  for (int i = 0; i < 8; ++i) {
    bf16x8 v = *(const bf16x8*)(row + i * 8);
#pragma unroll
    for (int j = 0; j < 8; ++j) s += (float)v[j] * bqs[hd * 64 + i * 8 + j];
  }
  beta[((size_t)b * 4 + hd) * 1600 + q] = (bf16)s;
}

// ===========================================================================
// stream_score3: i-chunks of 32 per block (8 cids x 2 sub-chunks of 16).
// LDS: single 20KB T-window (64 rows x 160 q) -> ~7 blocks/CU (was 2 at 50KB).
// Window 160 covers the max 3-source-row span; qbase 40-aligned (80B = 16B ok).
// Partial score planes scorep[cid]; beta folded into cid 0.
// ===========================================================================
__global__ __launch_bounds__(256, 6)
void stream_score3(const float* __restrict__ query, const bf16* __restrict__ T,
                   const bf16* __restrict__ beta, float* __restrict__ scorep) {
  __shared__ alignas(16) bf16 Ts[64][160];  // 20KB
  __shared__ bf16 Bs[4][160];
  const int t = threadIdx.x;
  const int ptile = blockIdx.x >> 3;
  const int cid = blockIdx.x & 7;
  const int p0 = ptile * 256;
  const int b = blockIdx.y;
  const int px = p0 + t;
  const int x = px / 80, y = px % 80;

  // block-uniform q-window base
  const int x_min = p0 / 80;
  int ixm = (int)floorf(0.5f * x_min - 0.25f);
  int xr0 = ixm < 0 ? 0 : ixm;
  int qbase = xr0 * 40;
  if (qbase > 1440) qbase = 1440;

  // per-thread interp (registers)
  float cx = 0.5f * x - 0.25f;
  int ix = (int)floorf(cx);
  float wx1 = cx - ix;
  int x0 = ix < 0 ? 0 : ix, x1 = (ix + 1 > 39) ? 39 : ix + 1;
  float cy = 0.5f * y - 0.25f;
  int iy = (int)floorf(cy);
  float wy1 = cy - iy;
  int y0 = iy < 0 ? 0 : iy, y1 = (iy + 1 > 39) ? 39 : iy + 1;
  const float w00 = (1.f - wx1) * (1.f - wy1), w01 = (1.f - wx1) * wy1;
  const float w10 = wx1 * (1.f - wy1), w11 = wx1 * wy1;
  const int r00 = x0 * 40 + y0 - qbase, r01 = x0 * 40 + y1 - qbase;
  const int r10 = x1 * 40 + y0 - qbase, r11 = x1 * 40 + y1 - qbase;

  if (cid == 0) {
    for (int i = t; i < 640; i += 256) {
      int hd = i / 160, qq = i - hd * 160;
      Bs[hd][qq] = beta[((size_t)b * 4 + hd) * 1600 + qbase + qq];
    }
  }

  const bf16* Tb = T + (size_t)b * 4 * 256 * 1600;

  // stage 64 rows (4 hd x 16 i) x 160 q: 1280 units of 16B = 5 gl16/thread
  auto STAGE = [&](int ibase) {
#pragma unroll
    for (int call = 0; call < 5; ++call) {
      int idx = call * 256 + t;
      int r = idx / 20, u = idx - r * 20;
      int hd = r >> 4, kk = r & 15;
      const bf16* src = Tb + ((size_t)(hd * 256) + ibase + kk) * 1600 + qbase + u * 8;
      gl16(src, &Ts[0][0] + idx * 8);
    }
  };

  float acc[4];
  if (cid == 0) {
    // beta is in Bs after this block's own store; sync below covers it
#pragma unroll
    for (int hd = 0; hd < 4; ++hd) acc[hd] = 0.f;
  } else {
#pragma unroll
    for (int hd = 0; hd < 4; ++hd) acc[hd] = 0.f;
  }

  const int c0 = cid * 32;
#pragma unroll
  for (int s = 0; s < 2; ++s) {
    if (s) __syncthreads();            // retire previous compute's LDS reads
    STAGE(c0 + s * 16);
    asm volatile("s_waitcnt vmcnt(0)" ::: "memory");
    __syncthreads();
    if (s == 0 && cid == 0) {
#pragma unroll
      for (int hd = 0; hd < 4; ++hd)
        acc[hd] += w00 * (float)Bs[hd][r00] + w01 * (float)Bs[hd][r01] +
                   w10 * (float)Bs[hd][r10] + w11 * (float)Bs[hd][r11];
    }
    float qv[16];
#pragma unroll
    for (int kk = 0; kk < 16; ++kk)
      qv[kk] = query[((size_t)b * 256 + c0 + s * 16 + kk) * 6400 + px];
#pragma unroll
    for (int kk = 0; kk < 16; ++kk) {
#pragma unroll
      for (int hd = 0; hd < 4; ++hd) {
        const bf16* row = &Ts[hd * 16 + kk][0];
        float tv = w00 * (float)row[r00] + w01 * (float)row[r01] +
                   w10 * (float)row[r10] + w11 * (float)row[r11];
        acc[hd] += qv[kk] * tv;
      }
    }
  }

#pragma unroll
  for (int hd = 0; hd < 4; ++hd)
    scorep[(((size_t)cid * 16 + b) * 4 + hd) * 6400 + px] = 0.0625f * acc[hd];
}

// ---------------------------------------------------------------------------
// smax: sum 8 partial planes, then in-place column softmax over x (x4 folded).
// ---------------------------------------------------------------------------
__global__ void smax_kernel(const float* __restrict__ scorep, float* __restrict__ score) {
  __shared__ float s[6400];
  const int hd = blockIdx.x, b = blockIdx.y, t = threadIdx.x;
  float* buf = score + ((size_t)b * 4 + hd) * 6400;
  for (int i = t; i < 6400; i += 256) {
    float v = 0.f;
#pragma unroll
    for (int c = 0; c < 8; ++c)
      v += scorep[(((size_t)c * 16 + b) * 4 + hd) * 6400 + i];
    s[i] = v;
  }
  __syncthreads();
  if (t < 80) {
    const int y = t;
    float m = -1e30f;
    for (int x = 0; x < 80; ++x) m = fmaxf(m, s[x * 80 + y]);
    float sum = 0.f;
    for (int x = 0; x < 80; ++x) {
      float e = __expf(s[x * 80 + y] - m);
      s[x * 80 + y] = e;
      sum += e;
    }
    float inv = 4.0f / sum;
    for (int x = 0; x < 80; ++x) buf[x * 80 + y] = s[x * 80 + y] * inv;
  }
}

// ===========================================================================
// combine (unchanged): one block per (o, b), coalesced writes.
// ===========================================================================
__global__ __launch_bounds__(256, 8)
void combine(const bf16* __restrict__ Uv, const float* __restrict__ attn,
             const float* __restrict__ bo, float* __restrict__ out) {
  __shared__ bf16 Us[4][1600];
  __shared__ int   sx0[80], sx1[80];
  __shared__ float swx[80];
  const int t = threadIdx.x;
  const int o = blockIdx.x;
  const int b = blockIdx.y;

  const bf16* usrc = Uv + (size_t)(b * 4) * 256 * 1600 + (size_t)o * 1600;
  for (int idx = t; idx < 800; idx += 256) {
    int hd = idx / 200, u = idx % 200;
    *(bf16x8*)&Us[hd][u * 8] = *(const bf16x8*)(usrc + (size_t)hd * 256 * 1600 + u * 8);
  }
  if (t < 80) {
    float c = 0.5f * t - 0.25f;
    int i0 = (int)floorf(c);
    swx[t] = c - i0;
    sx0[t] = i0 < 0 ? 0 : i0;
    sx1[t] = (i0 + 1 > 39) ? 39 : i0 + 1;
  }
  __syncthreads();

  const float bias = bo[o];
  const float* attb = attn + (size_t)b * 4 * 6400;
  float* op = out + ((size_t)b * 256 + o) * 6400;

  for (int p = t; p < 6400; p += 256) {
    int x = p / 80, y = p - x * 80;
    int x0 = sx0[x], x1 = sx1[x], y0 = sx0[y], y1 = sx1[y];
    float wx1 = swx[x], wy1 = swx[y];
    float w00 = (1.f - wx1) * (1.f - wy1), w01 = (1.f - wx1) * wy1;
    float w10 = wx1 * (1.f - wy1), w11 = wx1 * wy1;
    int q00 = x0 * 40 + y0, q01 = x0 * 40 + y1, q10 = x1 * 40 + y0, q11 = x1 * 40 + y1;
    float acc = bias;
#pragma unroll
    for (int hd = 0; hd < 4; ++hd) {
      float up = w00 * (float)Us[hd][q00] + w01 * (float)Us[hd][q01] +
                 w10 * (float)Us[hd][q10] + w11 * (float)Us[hd][q11];
      acc += attb[hd * 6400 + p] * up;
    }
    op[p] = acc;
  }
}

// ---------------------------------------------------------------------------
extern "C" void kernel_launch(void* const* d_in, const int* in_sizes, int n_in,
                              void* d_out, int out_size, void* d_ws, size_t ws_size,
                              hipStream_t stream) {
  const float* query = (const float*)d_in[0];
  const float* key   = (const float*)d_in[1];
  const float* wq    = (const float*)d_in[2];
  const float* bq    = (const float*)d_in[3];
  const float* wk    = (const float*)d_in[4];
  const float* bk    = (const float*)d_in[5];
  const float* wv    = (const float*)d_in[6];
  const float* bv    = (const float*)d_in[7];
  const float* wo    = (const float*)d_in[8];
  const float* bo    = (const float*)d_in[9];

  // ws (85.7MB): [T | later Uv] | Kpm | Vpm | score | Wb.
  // d_out scratch (dead before combine): wqT | beta | scorep (13.1MB).
  char* ws = (char*)d_ws;
  bf16*  T     = (bf16*)(ws);              // 52,428,800 B (dead after stream_score3)
  bf16*  Uv    = (bf16*)(ws);              // written by uv_gemm (after smax)
  bf16*  Kpm   = (bf16*)(ws + 52428800);   // 13,107,200 B
  bf16*  Vpm   = (bf16*)(ws + 65536000);   // 13,107,200 B
  float* score = (float*)(ws + 78643200);  //  6,553,600 B
  bf16*  Wb    = (bf16*)(ws + 85196800);   //    524,288 B
  bf16* wkb = Wb + 65536, *wvb = Wb + 131072, *wob = Wb + 196608;
  bf16*  wqT    = (bf16*)d_out;                      //   131,072 B scratch
  bf16*  beta   = (bf16*)((char*)d_out + 131072);    //   204,800 B scratch
  float* scorep = (float*)((char*)d_out + 1048576);  // 13,107,200 B scratch

  wpre<<<dim3(32, 4), 256, 0, stream>>>(wq, wk, wv, wo, Wb);
  wtr<<<dim3(4, 4), 256, 0, stream>>>(wq, wqT);
  kv_proj<<<dim3(25, 2, 16), 256, 0, stream>>>(key, wkb, bk, Kpm, wvb, bv, Vpm);
  uv_gemm<<<dim3(25, 4, 16), 256, 0, stream>>>(Kpm, wqT, T);    // T-gemm
  beta_k<<<dim3(25, 16), 256, 0, stream>>>(Kpm, bq, beta);
  stream_score3<<<dim3(200, 16), 256, 0, stream>>>(query, T, beta, scorep);
  smax_kernel<<<dim3(4, 16), 256, 0, stream>>>(scorep, score);
  uv_gemm<<<dim3(25, 4, 16), 256, 0, stream>>>(Vpm, wob, Uv);
  combine<<<dim3(256, 16), 256, 0, stream>>>(Uv, score, bo, (float*)d_out);
}

// Round 19
// 171.230 us; speedup vs baseline: 4.6471x; 4.6471x over previous
//
#include <hip/hip_runtime.h>
#include <hip/hip_bf16.h>

typedef __bf16 bf16;
typedef __attribute__((ext_vector_type(4))) float f32x4;
typedef __attribute__((ext_vector_type(8))) __bf16 bf16x8;
typedef __attribute__((ext_vector_type(4))) __bf16 bf16x4;

// async global->LDS, 16B per lane; LDS dest must be wave-uniform base + lane*16
static __device__ __forceinline__ void gl16(const void* g, void* l) {
  __builtin_amdgcn_global_load_lds((const __attribute__((address_space(1))) void*)g,
                                   (__attribute__((address_space(3))) void*)l, 16, 0, 0);
}
// fragment read from a [*][64] bf16 tile, 16B-unit XOR swizzle by (row&7)
static __device__ __forceinline__ bf16x8 frag(const bf16* tile, int row, int kb) {
  return *(const bf16x8*)(tile + row * 64 + ((((kb) >> 3) ^ (row & 7)) << 3));
}

// ---------------------------------------------------------------------------
// Weight prepass: 4x [256][256] f32 -> bf16 row-major.
// ---------------------------------------------------------------------------
__global__ void wpre(const float* __restrict__ w0, const float* __restrict__ w1,
                     const float* __restrict__ w2, const float* __restrict__ w3,
                     bf16* __restrict__ dst) {
  const float* srcs[4] = {w0, w1, w2, w3};
  const float* s = srcs[blockIdx.y];
  bf16* d = dst + (size_t)blockIdx.y * 65536;
  int base = blockIdx.x * 2048 + threadIdx.x * 8;
  f32x4 a = *(const f32x4*)(s + base);
  f32x4 b = *(const f32x4*)(s + base + 4);
  bf16x8 v = {(bf16)a[0], (bf16)a[1], (bf16)a[2], (bf16)a[3],
              (bf16)b[0], (bf16)b[1], (bf16)b[2], (bf16)b[3]};
  *(bf16x8*)(d + base) = v;
}

// ===========================================================================
// Fused Q-projection + score (R8/R13 structure — empirical best).
// ===========================================================================
__global__ __launch_bounds__(256, 3)
void qscore(const float* __restrict__ query, const bf16* __restrict__ Wq,
            const float* __restrict__ bq, const bf16* __restrict__ Kpm,
            float* __restrict__ score) {
  __shared__ alignas(16) char smem[64 * 264 * 2];
  const int t = threadIdx.x;
  const int b = blockIdx.z;
  const int p0 = blockIdx.x * 64;
  const int w = t >> 6, l = t & 63;
  const int lrow = l & 15, ksel = l >> 4;
  const int pq = t & 15, cq = t >> 4;
  const float* actb = query + (size_t)b * 256 * 6400;

  auto Bt = [&](int buf) { return (bf16*)(smem + buf * 8192); };

  f32x4 Ar[4];
  auto ALOAD = [&](int kt) {
    const int k0 = kt * 64;
#pragma unroll
    for (int j = 0; j < 4; ++j)
      Ar[j] = *(const f32x4*)(actb + (size_t)(k0 + cq * 4 + j) * 6400 + p0 + pq * 4);
  };
  auto ASTORE = [&](int buf) {
    bf16* tile = Bt(buf);
#pragma unroll
    for (int e = 0; e < 4; ++e) {
      int row = pq * 4 + e;
      bf16x4 v = {(bf16)Ar[0][e], (bf16)Ar[1][e], (bf16)Ar[2][e], (bf16)Ar[3][e]};
      *(bf16x4*)(tile + row * 64 + ((((cq >> 1) ^ (row & 7)) << 3) | ((cq & 1) << 2))) = v;
    }
  };

  f32x4 acc[4][4];
#pragma unroll
  for (int i = 0; i < 4; ++i)
#pragma unroll
    for (int j = 0; j < 4; ++j) acc[i][j] = (f32x4){0.f, 0.f, 0.f, 0.f};

  auto COMPUTE = [&](int kt, int buf) {
    const int k0 = kt * 64;
    bf16x8 af[4][2];
#pragma unroll
    for (int mi = 0; mi < 4; ++mi)
#pragma unroll
      for (int kk = 0; kk < 2; ++kk)
        af[mi][kk] = *(const bf16x8*)(Wq + (size_t)(w * 64 + mi * 16 + lrow) * 256 +
                                      k0 + kk * 32 + ksel * 8);
    bf16x8 bv[4][2];
#pragma unroll
    for (int ni = 0; ni < 4; ++ni)
#pragma unroll
      for (int kk = 0; kk < 2; ++kk)
        bv[ni][kk] = frag(Bt(buf), ni * 16 + lrow, kk * 32 + ksel * 8);
#pragma unroll
    for (int kk = 0; kk < 2; ++kk)
#pragma unroll
      for (int mi = 0; mi < 4; ++mi)
#pragma unroll
        for (int ni = 0; ni < 4; ++ni)
          acc[mi][ni] = __builtin_amdgcn_mfma_f32_16x16x32_bf16(af[mi][kk], bv[ni][kk],
                                                                acc[mi][ni], 0, 0, 0);
  };

  ALOAD(0);
  ASTORE(0);
  __syncthreads();
#pragma unroll
  for (int kt = 0; kt < 4; ++kt) {
    if (kt < 3) ALOAD(kt + 1);
    COMPUTE(kt, kt & 1);
    if (kt < 3) ASTORE((kt + 1) & 1);
    __syncthreads();
  }

  __syncthreads();
  bf16* Qs = (bf16*)smem;
#pragma unroll
  for (int mi = 0; mi < 4; ++mi) {
#pragma unroll
    for (int r = 0; r < 4; ++r) {
      int o = w * 64 + mi * 16 + ksel * 4 + r;
      float bvf = bq[o];
#pragma unroll
      for (int ni = 0; ni < 4; ++ni) {
        int px = ni * 16 + lrow;
        Qs[px * 264 + o] = (bf16)(acc[mi][ni][r] + bvf);
      }
    }
  }
  __syncthreads();

  {
    int pl = t & 63, hd = t >> 6;
    int p = p0 + pl;
    int x = p / 80, y = p % 80;
    float cx = 0.5f * x - 0.25f;
    int ix = (int)floorf(cx);
    float wx1 = cx - ix;
    int x0 = ix < 0 ? 0 : ix, x1 = (ix + 1 > 39) ? 39 : ix + 1;
    float cy = 0.5f * y - 0.25f;
    int iy = (int)floorf(cy);
    float wy1 = cy - iy;
    int y0 = iy < 0 ? 0 : iy, y1 = (iy + 1 > 39) ? 39 : iy + 1;
    float w00 = (1.f - wx1) * (1.f - wy1), w01 = (1.f - wx1) * wy1;
    float w10 = wx1 * (1.f - wy1), w11 = wx1 * wy1;
    const bf16* k00 = Kpm + ((size_t)b * 1600 + x0 * 40 + y0) * 256 + hd * 64;
    const bf16* k01 = Kpm + ((size_t)b * 1600 + x0 * 40 + y1) * 256 + hd * 64;
    const bf16* k10 = Kpm + ((size_t)b * 1600 + x1 * 40 + y0) * 256 + hd * 64;
    const bf16* k11 = Kpm + ((size_t)b * 1600 + x1 * 40 + y1) * 256 + hd * 64;
    float dot = 0.f;
#pragma unroll
    for (int i = 0; i < 8; ++i) {
      bf16x8 qv = *(const bf16x8*)(Qs + pl * 264 + hd * 64 + i * 8);
      bf16x8 a = *(const bf16x8*)(k00 + i * 8);
      bf16x8 c = *(const bf16x8*)(k01 + i * 8);
      bf16x8 d = *(const bf16x8*)(k10 + i * 8);
      bf16x8 e = *(const bf16x8*)(k11 + i * 8);
#pragma unroll
      for (int j = 0; j < 8; ++j) {
        float kup = w00 * (float)a[j] + w01 * (float)c[j] + w10 * (float)d[j] + w11 * (float)e[j];
        dot += (float)qv[j] * kup;
      }
    }
    score[((size_t)b * 4 + hd) * 6400 + p] = dot * 0.0625f;
  }
}

// ---------------------------------------------------------------------------
// K+V projection (R7/R13 structure).
// ---------------------------------------------------------------------------
__global__ __launch_bounds__(512, 1)
void kv_gemm(const float* __restrict__ key,
             const bf16* __restrict__ Wk, const float* __restrict__ bk, bf16* __restrict__ Kpm,
             const bf16* __restrict__ Wv, const float* __restrict__ bv, bf16* __restrict__ Vpm) {
  __shared__ alignas(16) char smem[65536];
  const int P = 1600;
  const int t = threadIdx.x;
  const int b = blockIdx.z;
  const int m0 = blockIdx.x * 128;
  const int sel = blockIdx.y >> 1;
  const int n0 = (blockIdx.y & 1) * 128;
  const bf16* W = sel ? Wv : Wk;
  const float* bias = sel ? bv : bk;
  bf16* out = sel ? Vpm : Kpm;
  const int w = t >> 6, l = t & 63;
  const int wr = w & 1, wc = w >> 1;
  const int lrow = l & 15, koff = (l >> 4) * 8;
  const int up = t & 31, uk = t >> 5;
  const float* actb = key + (size_t)b * 256 * P;

  f32x4 Ar[4];
  f32x4 acc[4][2];
#pragma unroll
  for (int i = 0; i < 4; ++i)
#pragma unroll
    for (int j = 0; j < 2; ++j) acc[i][j] = (f32x4){0.f, 0.f, 0.f, 0.f};

  auto Ab = [&](int buf) { return (bf16*)(smem + buf * 16384); };
  auto Bb = [&](int buf) { return (bf16*)(smem + 32768 + buf * 16384); };

  auto GLOADB = [&](int kt, int buf) {
    const int k0 = kt * 64;
#pragma unroll
    for (int call = 0; call < 2; ++call) {
      int idx = call * 512 + t;
      int row = idx >> 3, u = idx & 7;
      gl16(W + (size_t)(n0 + row) * 256 + k0 + ((u ^ (row & 7)) << 3), Bb(buf) + idx * 8);
    }
  };
  auto ALOAD = [&](int kt) {
    const int k0 = kt * 64;
    int ps = m0 + up * 4;
    if (ps > P - 4) ps = P - 4;
#pragma unroll
    for (int j = 0; j < 4; ++j)
      Ar[j] = *(const f32x4*)(actb + (size_t)(k0 + uk * 4 + j) * P + ps);
  };
  auto ASTORE = [&](int buf) {
#pragma unroll
    for (int j = 0; j < 4; ++j) {
      int row = up * 4 + j;
      int cs = (uk * 4) ^ ((row & 7) << 3);
      bf16x4 v = {(bf16)Ar[0][j], (bf16)Ar[1][j], (bf16)Ar[2][j], (bf16)Ar[3][j]};
      *(bf16x4*)(Ab(buf) + row * 64 + cs) = v;
    }
  };
  auto COMPUTE = [&](int buf) {
#pragma unroll
    for (int kk = 0; kk < 2; ++kk) {
      bf16x8 af[4], bvv[2];
      const int kb = kk * 32 + koff;
#pragma unroll
      for (int i = 0; i < 4; ++i) af[i] = frag(Ab(buf), wr * 64 + i * 16 + lrow, kb);
#pragma unroll
      for (int j = 0; j < 2; ++j) bvv[j] = frag(Bb(buf), wc * 32 + j * 16 + lrow, kb);
#pragma unroll
      for (int i = 0; i < 4; ++i)
#pragma unroll
        for (int j = 0; j < 2; ++j)
          acc[i][j] = __builtin_amdgcn_mfma_f32_16x16x32_bf16(af[i], bvv[j], acc[i][j], 0, 0, 0);
    }
  };

  GLOADB(0, 0);
  ALOAD(0);
  ASTORE(0);
  __syncthreads();
#pragma unroll
  for (int kt = 0; kt < 4; ++kt) {
    const int cur = kt & 1;
    if (kt < 3) { GLOADB(kt + 1, cur ^ 1); ALOAD(kt + 1); }
    __builtin_amdgcn_sched_barrier(0);
    COMPUTE(cur);
    if (kt < 3) ASTORE(cur ^ 1);
    __syncthreads();
  }

  bf16* Sc = (bf16*)smem;
#pragma unroll
  for (int mi = 0; mi < 4; ++mi) {
#pragma unroll
    for (int ni = 0; ni < 2; ++ni) {
      int ch = wc * 32 + ni * 16 + (l & 15);
      float bvf = bias[n0 + ch];
#pragma unroll
      for (int r = 0; r < 4; ++r) {
        int p = wr * 64 + mi * 16 + (l >> 4) * 4 + r;
        Sc[p * 136 + ch] = (bf16)(acc[mi][ni][r] + bvf);
      }
    }
  }
  __syncthreads();
  bf16* ob = out + (size_t)b * P * 256;
#pragma unroll
  for (int pass = 0; pass < 4; ++pass) {
    int unit = pass * 512 + t;
    int row = unit >> 4, cu = unit & 15;
    if (m0 + row < P) {
      bf16x8 v = *(const bf16x8*)(Sc + row * 136 + cu * 8);
      *(bf16x8*)(ob + (size_t)(m0 + row) * 256 + n0 + cu * 8) = v;
    }
  }
}

// ---------------------------------------------------------------------------
// In-place column softmax over x (per b,hd,y), x4 (R2 sum) folded in.
// ---------------------------------------------------------------------------
__global__ void smax_kernel(float* __restrict__ score) {
  __shared__ float s[6400];
  const int hd = blockIdx.x, b = blockIdx.y, t = threadIdx.x;
  float* buf = score + ((size_t)b * 4 + hd) * 6400;
  for (int i = t; i < 6400; i += 256) s[i] = buf[i];
  __syncthreads();
  if (t < 80) {
    const int y = t;
    float m = -1e30f;
    for (int x = 0; x < 80; ++x) m = fmaxf(m, s[x * 80 + y]);
    float sum = 0.f;
    for (int x = 0; x < 80; ++x) {
      float e = __expf(s[x * 80 + y] - m);
      s[x * 80 + y] = e;
      sum += e;
    }
    float inv = 4.0f / sum;
    for (int x = 0; x < 80; ++x) buf[x * 80 + y] = s[x * 80 + y] * inv;
  }
}

// ===========================================================================
// Uv[b][hd][o][q] = sum_{c<64} wo[o][hd*64+c] * V[b][q][hd*64+c]
// ===========================================================================
__global__ __launch_bounds__(256, 4)
void uv_gemm(const bf16* __restrict__ Vpm, const bf16* __restrict__ Wo,
             bf16* __restrict__ Uv) {
  __shared__ alignas(16) bf16 Vt[64 * 64];
  const int t = threadIdx.x;
  const int b = blockIdx.z;
  const int hd = blockIdx.y;
  const int q0 = blockIdx.x * 64;
  const int w = t >> 6, l = t & 63;
  const int lrow = l & 15, ksel = l >> 4;

  const bf16* vsrc = Vpm + ((size_t)b * 1600 + q0) * 256 + hd * 64;
#pragma unroll
  for (int call = 0; call < 2; ++call) {
    int idx = (w * 2 + call) * 64 + l;
    int q = idx >> 3, u = idx & 7;
    gl16(vsrc + (size_t)q * 256 + ((u ^ (q & 7)) << 3), Vt + idx * 8);
  }
  asm volatile("s_waitcnt vmcnt(0)" ::: "memory");
  __syncthreads();

  f32x4 acc[4][4];
#pragma unroll
  for (int i = 0; i < 4; ++i)
#pragma unroll
    for (int j = 0; j < 4; ++j) acc[i][j] = (f32x4){0.f, 0.f, 0.f, 0.f};

#pragma unroll
  for (int kk = 0; kk < 2; ++kk) {
    bf16x8 af[4], bv[4];
#pragma unroll
    for (int mi = 0; mi < 4; ++mi)
      af[mi] = *(const bf16x8*)(Wo + (size_t)(w * 64 + mi * 16 + lrow) * 256 +
                                hd * 64 + kk * 32 + ksel * 8);
#pragma unroll
    for (int ni = 0; ni < 4; ++ni)
      bv[ni] = frag(Vt, ni * 16 + lrow, kk * 32 + ksel * 8);
#pragma unroll
    for (int mi = 0; mi < 4; ++mi)
#pragma unroll
      for (int ni = 0; ni < 4; ++ni)
        acc[mi][ni] = __builtin_amdgcn_mfma_f32_16x16x32_bf16(af[mi], bv[ni], acc[mi][ni], 0, 0, 0);
  }

  bf16* ob = Uv + ((size_t)(b * 4 + hd)) * 256 * 1600;
#pragma unroll
  for (int mi = 0; mi < 4; ++mi) {
#pragma unroll
    for (int ni = 0; ni < 4; ++ni) {
#pragma unroll
      for (int r = 0; r < 4; ++r) {
        int o = w * 64 + mi * 16 + ksel * 4 + r;
        int q = q0 + ni * 16 + lrow;
        ob[(size_t)o * 1600 + q] = (bf16)acc[mi][ni][r];
      }
    }
  }
}

// ===========================================================================
// combine: one block per (o, b) -> fully coalesced output writes.
// ===========================================================================
__global__ __launch_bounds__(256, 8)
void combine(const bf16* __restrict__ Uv, const float* __restrict__ attn,
             const float* __restrict__ bo, float* __restrict__ out) {
  __shared__ bf16 Us[4][1600];
  __shared__ int   sx0[80], sx1[80];
  __shared__ float swx[80];
  const int t = threadIdx.x;
  const int o = blockIdx.x;
  const int b = blockIdx.y;

  const bf16* usrc = Uv + (size_t)(b * 4) * 256 * 1600 + (size_t)o * 1600;
  for (int idx = t; idx < 800; idx += 256) {
    int hd = idx / 200, u = idx % 200;
    *(bf16x8*)&Us[hd][u * 8] = *(const bf16x8*)(usrc + (size_t)hd * 256 * 1600 + u * 8);
  }
  if (t < 80) {
    float c = 0.5f * t - 0.25f;
    int i0 = (int)floorf(c);
    swx[t] = c - i0;
    sx0[t] = i0 < 0 ? 0 : i0;
    sx1[t] = (i0 + 1 > 39) ? 39 : i0 + 1;
  }
  __syncthreads();

  const float bias = bo[o];
  const float* attb = attn + (size_t)b * 4 * 6400;
  float* op = out + ((size_t)b * 256 + o) * 6400;

  for (int p = t; p < 6400; p += 256) {
    int x = p / 80, y = p - x * 80;
    int x0 = sx0[x], x1 = sx1[x], y0 = sx0[y], y1 = sx1[y];
    float wx1 = swx[x], wy1 = swx[y];
    float w00 = (1.f - wx1) * (1.f - wy1), w01 = (1.f - wx1) * wy1;
    float w10 = wx1 * (1.f - wy1), w11 = wx1 * wy1;
    int q00 = x0 * 40 + y0, q01 = x0 * 40 + y1, q10 = x1 * 40 + y0, q11 = x1 * 40 + y1;
    float acc = bias;
#pragma unroll
    for (int hd = 0; hd < 4; ++hd) {
      float up = w00 * (float)Us[hd][q00] + w01 * (float)Us[hd][q01] +
                 w10 * (float)Us[hd][q10] + w11 * (float)Us[hd][q11];
      acc += attb[hd * 6400 + p] * up;
    }
    op[p] = acc;
  }
}

// ---------------------------------------------------------------------------
extern "C" void kernel_launch(void* const* d_in, const int* in_sizes, int n_in,
                              void* d_out, int out_size, void* d_ws, size_t ws_size,
                              hipStream_t stream) {
  const float* query = (const float*)d_in[0];
  const float* key   = (const float*)d_in[1];
  const float* wq    = (const float*)d_in[2];
  const float* bq    = (const float*)d_in[3];
  const float* wk    = (const float*)d_in[4];
  const float* bk    = (const float*)d_in[5];
  const float* wv    = (const float*)d_in[6];
  const float* bv    = (const float*)d_in[7];
  const float* wo    = (const float*)d_in[8];
  const float* bo    = (const float*)d_in[9];

  // ws layout (85.7 MB): Uv | Kpm | Vpm | score(+attn in-place) | Wb
  char* ws = (char*)d_ws;
  bf16*  Uv    = (bf16*)(ws);              // 52,428,800 B  [b][hd][o][q]
  bf16*  Kpm   = (bf16*)(ws + 52428800);   // 13,107,200 B
  bf16*  Vpm   = (bf16*)(ws + 65536000);   // 13,107,200 B
  float* score = (float*)(ws + 78643200);  //  6,553,600 B
  bf16*  Wb    = (bf16*)(ws + 85196800);   //    524,288 B: wq,wk,wv,wo bf16
  bf16* wqb = Wb, *wkb = Wb + 65536, *wvb = Wb + 131072, *wob = Wb + 196608;

  wpre<<<dim3(32, 4), 256, 0, stream>>>(wq, wk, wv, wo, Wb);
  kv_gemm<<<dim3(13, 4, 16), 512, 0, stream>>>(key, wkb, bk, Kpm, wvb, bv, Vpm);
  qscore<<<dim3(100, 1, 16), 256, 0, stream>>>(query, wqb, bq, Kpm, score);
  smax_kernel<<<dim3(4, 16), 256, 0, stream>>>(score);
  uv_gemm<<<dim3(25, 4, 16), 256, 0, stream>>>(Vpm, wob, Uv);
  combine<<<dim3(256, 16), 256, 0, stream>>>(Uv, score, bo, (float*)d_out);
}

// Round 20
// 170.857 us; speedup vs baseline: 4.6573x; 1.0022x over previous
//
#include <hip/hip_runtime.h>
#include <hip/hip_bf16.h>

typedef __bf16 bf16;
typedef __attribute__((ext_vector_type(4))) float f32x4;
typedef __attribute__((ext_vector_type(8))) __bf16 bf16x8;
typedef __attribute__((ext_vector_type(4))) __bf16 bf16x4;

// async global->LDS, 16B per lane; LDS dest must be wave-uniform base + lane*16
static __device__ __forceinline__ void gl16(const void* g, void* l) {
  __builtin_amdgcn_global_load_lds((const __attribute__((address_space(1))) void*)g,
                                   (__attribute__((address_space(3))) void*)l, 16, 0, 0);
}
// fragment read from a [*][64] bf16 tile, 16B-unit XOR swizzle by (row&7)
static __device__ __forceinline__ bf16x8 frag(const bf16* tile, int row, int kb) {
  return *(const bf16x8*)(tile + row * 64 + ((((kb) >> 3) ^ (row & 7)) << 3));
}

// ---------------------------------------------------------------------------
// Weight prepass: 4x [256][256] f32 -> bf16 row-major.
// ---------------------------------------------------------------------------
__global__ void wpre(const float* __restrict__ w0, const float* __restrict__ w1,
                     const float* __restrict__ w2, const float* __restrict__ w3,
                     bf16* __restrict__ dst) {
  const float* srcs[4] = {w0, w1, w2, w3};
  const float* s = srcs[blockIdx.y];
  bf16* d = dst + (size_t)blockIdx.y * 65536;
  int base = blockIdx.x * 2048 + threadIdx.x * 8;
  f32x4 a = *(const f32x4*)(s + base);
  f32x4 b = *(const f32x4*)(s + base + 4);
  bf16x8 v = {(bf16)a[0], (bf16)a[1], (bf16)a[2], (bf16)a[3],
              (bf16)b[0], (bf16)b[1], (bf16)b[2], (bf16)b[3]};
  *(bf16x8*)(d + base) = v;
}

// ===========================================================================
// MERGED: qscore (blocks x<100) + uv_gemm (blocks x>=100).
// qscore: R13 structure + prefetch-depth-2 (ALOAD(kt+2) issued a full phase
// before its ASTORE -> less exposed HBM latency per phase).
// uv: verbatim R19 body; fills CU slots while qscore waves stall.
// ===========================================================================
__global__ __launch_bounds__(256, 3)
void qscore_uv(const float* __restrict__ query, const bf16* __restrict__ Wq,
               const float* __restrict__ bq, const bf16* __restrict__ Kpm,
               float* __restrict__ score,
               const bf16* __restrict__ Vpm, const bf16* __restrict__ Wo,
               bf16* __restrict__ Uv) {
  __shared__ alignas(16) char smem[64 * 264 * 2];
  const int t = threadIdx.x;
  const int b = blockIdx.y;
  const int w = t >> 6, l = t & 63;
  const int lrow = l & 15, ksel = l >> 4;

  if (blockIdx.x >= 100) {
    // ---------------- uv_gemm path ----------------
    const int u = blockIdx.x - 100;
    const int q0 = (u % 25) * 64;
    const int hd = u / 25;
    bf16* Vt = (bf16*)smem;  // 8KB

    const bf16* vsrc = Vpm + ((size_t)b * 1600 + q0) * 256 + hd * 64;
#pragma unroll
    for (int call = 0; call < 2; ++call) {
      int idx = (w * 2 + call) * 64 + l;
      int q = idx >> 3, uu = idx & 7;
      gl16(vsrc + (size_t)q * 256 + ((uu ^ (q & 7)) << 3), Vt + idx * 8);
    }
    asm volatile("s_waitcnt vmcnt(0)" ::: "memory");
    __syncthreads();

    f32x4 acc[4][4];
#pragma unroll
    for (int i = 0; i < 4; ++i)
#pragma unroll
      for (int j = 0; j < 4; ++j) acc[i][j] = (f32x4){0.f, 0.f, 0.f, 0.f};

#pragma unroll
    for (int kk = 0; kk < 2; ++kk) {
      bf16x8 af[4], bv[4];
#pragma unroll
      for (int mi = 0; mi < 4; ++mi)
        af[mi] = *(const bf16x8*)(Wo + (size_t)(w * 64 + mi * 16 + lrow) * 256 +
                                  hd * 64 + kk * 32 + ksel * 8);
#pragma unroll
      for (int ni = 0; ni < 4; ++ni)
        bv[ni] = frag(Vt, ni * 16 + lrow, kk * 32 + ksel * 8);
#pragma unroll
      for (int mi = 0; mi < 4; ++mi)
#pragma unroll
        for (int ni = 0; ni < 4; ++ni)
          acc[mi][ni] = __builtin_amdgcn_mfma_f32_16x16x32_bf16(af[mi], bv[ni], acc[mi][ni], 0, 0, 0);
    }

    bf16* ob = Uv + ((size_t)(b * 4 + hd)) * 256 * 1600;
#pragma unroll
    for (int mi = 0; mi < 4; ++mi) {
#pragma unroll
      for (int ni = 0; ni < 4; ++ni) {
#pragma unroll
        for (int r = 0; r < 4; ++r) {
          int o = w * 64 + mi * 16 + ksel * 4 + r;
          int q = q0 + ni * 16 + lrow;
          ob[(size_t)o * 1600 + q] = (bf16)acc[mi][ni][r];
        }
      }
    }
    return;
  }

  // ---------------- qscore path ----------------
  const int p0 = blockIdx.x * 64;
  const int pq = t & 15, cq = t >> 4;
  const float* actb = query + (size_t)b * 256 * 6400;

  auto Bt = [&](int buf) { return (bf16*)(smem + buf * 8192); };

  f32x4 ArA[4], ArB[4];
  auto ALOAD = [&](int kt, f32x4* Ar) {
    const int k0 = kt * 64;
#pragma unroll
    for (int j = 0; j < 4; ++j)
      Ar[j] = *(const f32x4*)(actb + (size_t)(k0 + cq * 4 + j) * 6400 + p0 + pq * 4);
  };
  auto ASTORE = [&](const f32x4* Ar, int buf) {
    bf16* tile = Bt(buf);
#pragma unroll
    for (int e = 0; e < 4; ++e) {
      int row = pq * 4 + e;
      bf16x4 v = {(bf16)Ar[0][e], (bf16)Ar[1][e], (bf16)Ar[2][e], (bf16)Ar[3][e]};
      *(bf16x4*)(tile + row * 64 + ((((cq >> 1) ^ (row & 7)) << 3) | ((cq & 1) << 2))) = v;
    }
  };

  f32x4 acc[4][4];
#pragma unroll
  for (int i = 0; i < 4; ++i)
#pragma unroll
    for (int j = 0; j < 4; ++j) acc[i][j] = (f32x4){0.f, 0.f, 0.f, 0.f};

  auto COMPUTE = [&](int kt, int buf) {
    const int k0 = kt * 64;
    bf16x8 af[4][2];
#pragma unroll
    for (int mi = 0; mi < 4; ++mi)
#pragma unroll
      for (int kk = 0; kk < 2; ++kk)
        af[mi][kk] = *(const bf16x8*)(Wq + (size_t)(w * 64 + mi * 16 + lrow) * 256 +
                                      k0 + kk * 32 + ksel * 8);
    bf16x8 bv[4][2];
#pragma unroll
    for (int ni = 0; ni < 4; ++ni)
#pragma unroll
      for (int kk = 0; kk < 2; ++kk)
        bv[ni][kk] = frag(Bt(buf), ni * 16 + lrow, kk * 32 + ksel * 8);
#pragma unroll
    for (int kk = 0; kk < 2; ++kk)
#pragma unroll
      for (int mi = 0; mi < 4; ++mi)
#pragma unroll
        for (int ni = 0; ni < 4; ++ni)
          acc[mi][ni] = __builtin_amdgcn_mfma_f32_16x16x32_bf16(af[mi][kk], bv[ni][kk],
                                                                acc[mi][ni], 0, 0, 0);
  };

  // prologue: kt0 staged, kt1 in regs
  ALOAD(0, ArA);
  ASTORE(ArA, 0);
  ALOAD(1, ArB);
  __syncthreads();
  // phase0: issue kt2 early; compute kt0; stage kt1
  ALOAD(2, ArA);
  COMPUTE(0, 0);
  ASTORE(ArB, 1);
  __syncthreads();
  // phase1: issue kt3 early; compute kt1; stage kt2
  ALOAD(3, ArB);
  COMPUTE(1, 1);
  ASTORE(ArA, 0);
  __syncthreads();
  // phase2: compute kt2; stage kt3
  COMPUTE(2, 0);
  ASTORE(ArB, 1);
  __syncthreads();
  // phase3
  COMPUTE(3, 1);
  __syncthreads();  // retire LDS reads before Qs overwrite

  bf16* Qs = (bf16*)smem;
#pragma unroll
  for (int mi = 0; mi < 4; ++mi) {
#pragma unroll
    for (int r = 0; r < 4; ++r) {
      int o = w * 64 + mi * 16 + ksel * 4 + r;
      float bvf = bq[o];
#pragma unroll
      for (int ni = 0; ni < 4; ++ni) {
        int px = ni * 16 + lrow;
        Qs[px * 264 + o] = (bf16)(acc[mi][ni][r] + bvf);
      }
    }
  }
  __syncthreads();

  {
    int pl = t & 63, hd = t >> 6;
    int p = p0 + pl;
    int x = p / 80, y = p % 80;
    float cx = 0.5f * x - 0.25f;
    int ix = (int)floorf(cx);
    float wx1 = cx - ix;
    int x0 = ix < 0 ? 0 : ix, x1 = (ix + 1 > 39) ? 39 : ix + 1;
    float cy = 0.5f * y - 0.25f;
    int iy = (int)floorf(cy);
    float wy1 = cy - iy;
    int y0 = iy < 0 ? 0 : iy, y1 = (iy + 1 > 39) ? 39 : iy + 1;
    float w00 = (1.f - wx1) * (1.f - wy1), w01 = (1.f - wx1) * wy1;
    float w10 = wx1 * (1.f - wy1), w11 = wx1 * wy1;
    const bf16* k00 = Kpm + ((size_t)b * 1600 + x0 * 40 + y0) * 256 + hd * 64;
    const bf16* k01 = Kpm + ((size_t)b * 1600 + x0 * 40 + y1) * 256 + hd * 64;
    const bf16* k10 = Kpm + ((size_t)b * 1600 + x1 * 40 + y0) * 256 + hd * 64;
    const bf16* k11 = Kpm + ((size_t)b * 1600 + x1 * 40 + y1) * 256 + hd * 64;
    float dot = 0.f;
#pragma unroll
    for (int i = 0; i < 8; ++i) {
      bf16x8 qv = *(const bf16x8*)(Qs + pl * 264 + hd * 64 + i * 8);
      bf16x8 a = *(const bf16x8*)(k00 + i * 8);
      bf16x8 c = *(const bf16x8*)(k01 + i * 8);
      bf16x8 d = *(const bf16x8*)(k10 + i * 8);
      bf16x8 e = *(const bf16x8*)(k11 + i * 8);
#pragma unroll
      for (int j = 0; j < 8; ++j) {
        float kup = w00 * (float)a[j] + w01 * (float)c[j] + w10 * (float)d[j] + w11 * (float)e[j];
        dot += (float)qv[j] * kup;
      }
    }
    score[((size_t)b * 4 + hd) * 6400 + p] = dot * 0.0625f;
  }
}

// ---------------------------------------------------------------------------
// K+V projection (R7/R13 structure, unchanged).
// ---------------------------------------------------------------------------
__global__ __launch_bounds__(512, 1)
void kv_gemm(const float* __restrict__ key,
             const bf16* __restrict__ Wk, const float* __restrict__ bk, bf16* __restrict__ Kpm,
             const bf16* __restrict__ Wv, const float* __restrict__ bv, bf16* __restrict__ Vpm) {
  __shared__ alignas(16) char smem[65536];
  const int P = 1600;
  const int t = threadIdx.x;
  const int b = blockIdx.z;
  const int m0 = blockIdx.x * 128;
  const int sel = blockIdx.y >> 1;
  const int n0 = (blockIdx.y & 1) * 128;
  const bf16* W = sel ? Wv : Wk;
  const float* bias = sel ? bv : bk;
  bf16* out = sel ? Vpm : Kpm;
  const int w = t >> 6, l = t & 63;
  const int wr = w & 1, wc = w >> 1;
  const int lrow = l & 15, koff = (l >> 4) * 8;
  const int up = t & 31, uk = t >> 5;
  const float* actb = key + (size_t)b * 256 * P;

  f32x4 Ar[4];
  f32x4 acc[4][2];
#pragma unroll
  for (int i = 0; i < 4; ++i)
#pragma unroll
    for (int j = 0; j < 2; ++j) acc[i][j] = (f32x4){0.f, 0.f, 0.f, 0.f};

  auto Ab = [&](int buf) { return (bf16*)(smem + buf * 16384); };
  auto Bb = [&](int buf) { return (bf16*)(smem + 32768 + buf * 16384); };

  auto GLOADB = [&](int kt, int buf) {
    const int k0 = kt * 64;
#pragma unroll
    for (int call = 0; call < 2; ++call) {
      int idx = call * 512 + t;
      int row = idx >> 3, u = idx & 7;
      gl16(W + (size_t)(n0 + row) * 256 + k0 + ((u ^ (row & 7)) << 3), Bb(buf) + idx * 8);
    }
  };
  auto ALOAD = [&](int kt) {
    const int k0 = kt * 64;
    int ps = m0 + up * 4;
    if (ps > P - 4) ps = P - 4;
#pragma unroll
    for (int j = 0; j < 4; ++j)
      Ar[j] = *(const f32x4*)(actb + (size_t)(k0 + uk * 4 + j) * P + ps);
  };
  auto ASTORE = [&](int buf) {
#pragma unroll
    for (int j = 0; j < 4; ++j) {
      int row = up * 4 + j;
      int cs = (uk * 4) ^ ((row & 7) << 3);
      bf16x4 v = {(bf16)Ar[0][j], (bf16)Ar[1][j], (bf16)Ar[2][j], (bf16)Ar[3][j]};
      *(bf16x4*)(Ab(buf) + row * 64 + cs) = v;
    }
  };
  auto COMPUTE = [&](int buf) {
#pragma unroll
    for (int kk = 0; kk < 2; ++kk) {
      bf16x8 af[4], bvv[2];
      const int kb = kk * 32 + koff;
#pragma unroll
      for (int i = 0; i < 4; ++i) af[i] = frag(Ab(buf), wr * 64 + i * 16 + lrow, kb);
#pragma unroll
      for (int j = 0; j < 2; ++j) bvv[j] = frag(Bb(buf), wc * 32 + j * 16 + lrow, kb);
#pragma unroll
      for (int i = 0; i < 4; ++i)
#pragma unroll
        for (int j = 0; j < 2; ++j)
          acc[i][j] = __builtin_amdgcn_mfma_f32_16x16x32_bf16(af[i], bvv[j], acc[i][j], 0, 0, 0);
    }
  };

  GLOADB(0, 0);
  ALOAD(0);
  ASTORE(0);
  __syncthreads();
#pragma unroll
  for (int kt = 0; kt < 4; ++kt) {
    const int cur = kt & 1;
    if (kt < 3) { GLOADB(kt + 1, cur ^ 1); ALOAD(kt + 1); }
    __builtin_amdgcn_sched_barrier(0);
    COMPUTE(cur);
    if (kt < 3) ASTORE(cur ^ 1);
    __syncthreads();
  }

  bf16* Sc = (bf16*)smem;
#pragma unroll
  for (int mi = 0; mi < 4; ++mi) {
#pragma unroll
    for (int ni = 0; ni < 2; ++ni) {
      int ch = wc * 32 + ni * 16 + (l & 15);
      float bvf = bias[n0 + ch];
#pragma unroll
      for (int r = 0; r < 4; ++r) {
        int p = wr * 64 + mi * 16 + (l >> 4) * 4 + r;
        Sc[p * 136 + ch] = (bf16)(acc[mi][ni][r] + bvf);
      }
    }
  }
  __syncthreads();
  bf16* ob = out + (size_t)b * P * 256;
#pragma unroll
  for (int pass = 0; pass < 4; ++pass) {
    int unit = pass * 512 + t;
    int row = unit >> 4, cu = unit & 15;
    if (m0 + row < P) {
      bf16x8 v = *(const bf16x8*)(Sc + row * 136 + cu * 8);
      *(bf16x8*)(ob + (size_t)(m0 + row) * 256 + n0 + cu * 8) = v;
    }
  }
}

// ---------------------------------------------------------------------------
// In-place column softmax over x (per b,hd,y), x4 (R2 sum) folded in.
// ---------------------------------------------------------------------------
__global__ void smax_kernel(float* __restrict__ score) {
  __shared__ float s[6400];
  const int hd = blockIdx.x, b = blockIdx.y, t = threadIdx.x;
  float* buf = score + ((size_t)b * 4 + hd) * 6400;
  for (int i = t; i < 6400; i += 256) s[i] = buf[i];
  __syncthreads();
  if (t < 80) {
    const int y = t;
    float m = -1e30f;
    for (int x = 0; x < 80; ++x) m = fmaxf(m, s[x * 80 + y]);
    float sum = 0.f;
    for (int x = 0; x < 80; ++x) {
      float e = __expf(s[x * 80 + y] - m);
      s[x * 80 + y] = e;
      sum += e;
    }
    float inv = 4.0f / sum;
    for (int x = 0; x < 80; ++x) buf[x * 80 + y] = s[x * 80 + y] * inv;
  }
}

// ===========================================================================
// combine: one block per (o, b) -> fully coalesced output writes.
// ===========================================================================
__global__ __launch_bounds__(256, 8)
void combine(const bf16* __restrict__ Uv, const float* __restrict__ attn,
             const float* __restrict__ bo, float* __restrict__ out) {
  __shared__ bf16 Us[4][1600];
  __shared__ int   sx0[80], sx1[80];
  __shared__ float swx[80];
  const int t = threadIdx.x;
  const int o = blockIdx.x;
  const int b = blockIdx.y;

  const bf16* usrc = Uv + (size_t)(b * 4) * 256 * 1600 + (size_t)o * 1600;
  for (int idx = t; idx < 800; idx += 256) {
    int hd = idx / 200, u = idx % 200;
    *(bf16x8*)&Us[hd][u * 8] = *(const bf16x8*)(usrc + (size_t)hd * 256 * 1600 + u * 8);
  }
  if (t < 80) {
    float c = 0.5f * t - 0.25f;
    int i0 = (int)floorf(c);
    swx[t] = c - i0;
    sx0[t] = i0 < 0 ? 0 : i0;
    sx1[t] = (i0 + 1 > 39) ? 39 : i0 + 1;
  }
  __syncthreads();

  const float bias = bo[o];
  const float* attb = attn + (size_t)b * 4 * 6400;
  float* op = out + ((size_t)b * 256 + o) * 6400;

  for (int p = t; p < 6400; p += 256) {
    int x = p / 80, y = p - x * 80;
    int x0 = sx0[x], x1 = sx1[x], y0 = sx0[y], y1 = sx1[y];
    float wx1 = swx[x], wy1 = swx[y];
    float w00 = (1.f - wx1) * (1.f - wy1), w01 = (1.f - wx1) * wy1;
    float w10 = wx1 * (1.f - wy1), w11 = wx1 * wy1;
    int q00 = x0 * 40 + y0, q01 = x0 * 40 + y1, q10 = x1 * 40 + y0, q11 = x1 * 40 + y1;
    float acc = bias;
#pragma unroll
    for (int hd = 0; hd < 4; ++hd) {
      float up = w00 * (float)Us[hd][q00] + w01 * (float)Us[hd][q01] +
                 w10 * (float)Us[hd][q10] + w11 * (float)Us[hd][q11];
      acc += attb[hd * 6400 + p] * up;
    }
    op[p] = acc;
  }
}

// ---------------------------------------------------------------------------
extern "C" void kernel_launch(void* const* d_in, const int* in_sizes, int n_in,
                              void* d_out, int out_size, void* d_ws, size_t ws_size,
                              hipStream_t stream) {
  const float* query = (const float*)d_in[0];
  const float* key   = (const float*)d_in[1];
  const float* wq    = (const float*)d_in[2];
  const float* bq    = (const float*)d_in[3];
  const float* wk    = (const float*)d_in[4];
  const float* bk    = (const float*)d_in[5];
  const float* wv    = (const float*)d_in[6];
  const float* bv    = (const float*)d_in[7];
  const float* wo    = (const float*)d_in[8];
  const float* bo    = (const float*)d_in[9];

  // ws layout (85.7 MB): Uv | Kpm | Vpm | score(+attn in-place) | Wb
  char* ws = (char*)d_ws;
  bf16*  Uv    = (bf16*)(ws);              // 52,428,800 B  [b][hd][o][q]
  bf16*  Kpm   = (bf16*)(ws + 52428800);   // 13,107,200 B
  bf16*  Vpm   = (bf16*)(ws + 65536000);   // 13,107,200 B
  float* score = (float*)(ws + 78643200);  //  6,553,600 B
  bf16*  Wb    = (bf16*)(ws + 85196800);   //    524,288 B: wq,wk,wv,wo bf16
  bf16* wqb = Wb, *wkb = Wb + 65536, *wvb = Wb + 131072, *wob = Wb + 196608;

  wpre<<<dim3(32, 4), 256, 0, stream>>>(wq, wk, wv, wo, Wb);
  kv_gemm<<<dim3(13, 4, 16), 512, 0, stream>>>(key, wkb, bk, Kpm, wvb, bv, Vpm);
  qscore_uv<<<dim3(200, 16), 256, 0, stream>>>(query, wqb, bq, Kpm, score, Vpm, wob, Uv);
  smax_kernel<<<dim3(4, 16), 256, 0, stream>>>(score);
  combine<<<dim3(256, 16), 256, 0, stream>>>(Uv, score, bo, (float*)d_out);
}